// Round 1
// baseline (114.812 us; speedup 1.0000x reference)
//
#include <hip/hip_runtime.h>

#define DIN 512
#define DOUT 512

typedef int v4i __attribute__((ext_vector_type(4)));

// quantize one float to int8 (clamped), return low byte
__device__ __forceinline__ int q8f(float v, float s) {
    int i = (int)rintf(v / s);          // IEEE div + round-half-even, matches ref
    i = i < -128 ? -128 : (i > 127 ? 127 : i);
    return i & 255;
}

// ---------------- Kernel 1: global absmax of x ----------------
__global__ void absmax_kernel(const float4* __restrict__ x4, unsigned* __restrict__ amax, int n4) {
    float m = 0.f;
    int stride = gridDim.x * blockDim.x;
    for (int i = blockIdx.x * blockDim.x + threadIdx.x; i < n4; i += stride) {
        float4 v = x4[i];
        m = fmaxf(m, fmaxf(fmaxf(fabsf(v.x), fabsf(v.y)), fmaxf(fabsf(v.z), fabsf(v.w))));
    }
#pragma unroll
    for (int off = 32; off; off >>= 1) m = fmaxf(m, __shfl_xor(m, off));
    __shared__ float sm[4];
    int lane = threadIdx.x & 63, w = threadIdx.x >> 6;
    if (lane == 0) sm[w] = m;
    __syncthreads();
    if (threadIdx.x == 0) {
        m = fmaxf(fmaxf(sm[0], sm[1]), fmaxf(sm[2], sm[3]));
        atomicMax(amax, __float_as_uint(m));  // positive floats: uint bit compare == float compare
    }
}

// ---------------- Kernel 2: per-row weight quant + bias quant ----------------
__global__ void quantw_kernel(const float* __restrict__ w, const float* __restrict__ bias,
                              const unsigned* __restrict__ amax,
                              char* __restrict__ wq, float* __restrict__ cs, float* __restrict__ bq) {
    int gid = blockIdx.x * blockDim.x + threadIdx.x;
    int row = gid >> 6, lane = gid & 63;
    const float4* r4 = (const float4*)(w + (long)row * DIN);
    float4 a = r4[lane * 2];
    float4 b = r4[lane * 2 + 1];
    float m = fmaxf(fmaxf(fmaxf(fabsf(a.x), fabsf(a.y)), fmaxf(fabsf(a.z), fabsf(a.w))),
                    fmaxf(fmaxf(fabsf(b.x), fabsf(b.y)), fmaxf(fabsf(b.z), fabsf(b.w))));
#pragma unroll
    for (int off = 32; off; off >>= 1) m = fmaxf(m, __shfl_xor(m, off));
    float wsc = m / 127.0f;
    int lo = q8f(a.x, wsc) | (q8f(a.y, wsc) << 8) | (q8f(a.z, wsc) << 16) | (q8f(a.w, wsc) << 24);
    int hi = q8f(b.x, wsc) | (q8f(b.y, wsc) << 8) | (q8f(b.z, wsc) << 16) | (q8f(b.w, wsc) << 24);
    ((int2*)(wq + (long)row * DIN))[lane] = make_int2(lo, hi);
    if (lane == 0) {
        float as = __uint_as_float(*amax) / 127.0f;
        float bs = as * wsc;                 // combined scale
        float t  = rintf(bias[row] / bs);    // |t| ~ 1e3-1e4, 32-bit clip never fires
        cs[row] = bs;
        bq[row] = t * bs;
    }
}

// ---------------- Kernel 3: fused quantize-x + int8 MFMA GEMM ----------------
// BM=128, BN=512 (full N -> x read exactly once), BK=64.
// 512 threads = 8 waves as 2(m) x 4(n); wave tile 64x128 = 4x8 frags of 16x16.
// LDS tiles stored fragment-linear: chunk (row,kc) at index (row>>4)*64 + kc*16 + (row&15),
// so a fragment ds_read_b128 is base + lane*16 (lane-linear, conflict-free).
__global__ __launch_bounds__(512) void gemm_kernel(
    const float* __restrict__ x, const char* __restrict__ wq,
    const float* __restrict__ cs, const float* __restrict__ bq,
    const unsigned* __restrict__ amax, float* __restrict__ out) {
    __shared__ char xl[128 * 64];   // 8 KB int8
    __shared__ char wl[512 * 64];   // 32 KB int8
    const int t = threadIdx.x;
    const int lane = t & 63, wid = t >> 6;
    const int wm = wid >> 2, wn = wid & 3;
    const long rbase = (long)blockIdx.x * 128;
    const float as = __uint_as_float(*amax) / 127.0f;

    v4i acc[4][8] = {};

    // staging index precompute
    const int xrow0 = t >> 4;          // +j*32 ; 16 float4 per row
    const int xf4 = t & 15;
    const int xkc = xf4 >> 2, xd = xf4 & 3;
    const int wrow0 = t >> 2;          // +j*128 ; 4 int4 per row
    const int wkc = t & 3;

    for (int k0 = 0; k0 < DIN; k0 += 64) {
        // stage X: 128 rows x 64 cols fp32 -> int8, 4 rounds of float4 per thread
#pragma unroll
        for (int j = 0; j < 4; j++) {
            int row = j * 32 + xrow0;
            float4 v = *(const float4*)(x + (rbase + row) * DIN + k0 + xf4 * 4);
            int q = q8f(v.x, as) | (q8f(v.y, as) << 8) | (q8f(v.z, as) << 16) | (q8f(v.w, as) << 24);
            *(int*)(xl + ((row >> 4) * 64 + xkc * 16 + (row & 15)) * 16 + xd * 4) = q;
        }
        // stage W: 512 rows x 64 cols int8, 4 rounds of int4 per thread
#pragma unroll
        for (int j = 0; j < 4; j++) {
            int n = j * 128 + wrow0;
            int4 v = *(const int4*)(wq + (long)n * DIN + k0 + wkc * 16);
            *(int4*)(wl + ((n >> 4) * 64 + wkc * 16 + (n & 15)) * 16) = v;
        }
        __syncthreads();
        v4i bf[8];
#pragma unroll
        for (int ni = 0; ni < 8; ni++)
            bf[ni] = *(const v4i*)(wl + ((wn * 8 + ni) * 64 + lane) * 16);
#pragma unroll
        for (int mi = 0; mi < 4; mi++) {
            v4i af = *(const v4i*)(xl + ((wm * 4 + mi) * 64 + lane) * 16);
#pragma unroll
            for (int ni = 0; ni < 8; ni++)
                acc[mi][ni] = __builtin_amdgcn_mfma_i32_16x16x64_i8(af, bf[ni], acc[mi][ni], 0, 0, 0);
        }
        __syncthreads();
    }

    // epilogue: C/D layout col = lane&15, row = (lane>>4)*4 + r
    const int rloc = (lane >> 4) * 4;
    const int cloc = lane & 15;
#pragma unroll
    for (int ni = 0; ni < 8; ni++) {
        int col = wn * 128 + ni * 16 + cloc;
        float c = cs[col], b = bq[col];
#pragma unroll
        for (int mi = 0; mi < 4; mi++) {
            long grow = rbase + wm * 64 + mi * 16 + rloc;
#pragma unroll
            for (int r = 0; r < 4; r++) {
                out[(grow + r) * DOUT + col] = (float)acc[mi][ni][r] * c + b;
            }
        }
    }
}

extern "C" void kernel_launch(void* const* d_in, const int* in_sizes, int n_in,
                              void* d_out, int out_size, void* d_ws, size_t ws_size,
                              hipStream_t stream) {
    const float* x    = (const float*)d_in[0];
    const float* w    = (const float*)d_in[1];
    const float* bias = (const float*)d_in[2];
    float* out = (float*)d_out;
    const int M = in_sizes[0] / DIN;   // 65536

    char* ws = (char*)d_ws;
    unsigned* amax = (unsigned*)ws;
    char* wq  = ws + 64;
    float* cs = (float*)(ws + 64 + (long)DOUT * DIN);
    float* bq = cs + DOUT;

    hipMemsetAsync(d_ws, 0, 64, stream);                       // zero amax each call (ws not re-poisoned)
    absmax_kernel<<<2048, 256, 0, stream>>>((const float4*)x, amax, in_sizes[0] / 4);
    quantw_kernel<<<(DOUT * 64) / 256, 256, 0, stream>>>(w, bias, amax, wq, cs, bq);
    gemm_kernel<<<M / 128, 512, 0, stream>>>(x, wq, cs, bq, amax, out);
}

// Round 2
// 112.427 us; speedup vs baseline: 1.0212x; 1.0212x over previous
//
#include <hip/hip_runtime.h>

#define DIN 512
#define DOUT 512
#define BM 64
#define BK 64
#define NKSTEP (DIN / BK)

typedef int v4i __attribute__((ext_vector_type(4)));

// exact-divide quantize (weights/bias path, matches ref bit-for-bit)
__device__ __forceinline__ int q8f(float v, float s) {
    int i = (int)rintf(v / s);
    i = i < -128 ? -128 : (i > 127 ? 127 : i);
    return i & 255;
}
// multiply-by-reciprocal quantize (activation path; flip prob ~2^-22, err contribution ~0.005)
__device__ __forceinline__ int q8m(float v, float inv) {
    int i = (int)rintf(v * inv);
    i = i < -128 ? -128 : (i > 127 ? 127 : i);
    return i & 255;
}

// ---------------- Kernel 1: global absmax of x ----------------
__global__ void absmax_kernel(const float4* __restrict__ x4, unsigned* __restrict__ amax, int n4) {
    float m = 0.f;
    int stride = gridDim.x * blockDim.x;
    for (int i = blockIdx.x * blockDim.x + threadIdx.x; i < n4; i += stride) {
        float4 v = x4[i];
        m = fmaxf(m, fmaxf(fmaxf(fabsf(v.x), fabsf(v.y)), fmaxf(fabsf(v.z), fabsf(v.w))));
    }
#pragma unroll
    for (int off = 32; off; off >>= 1) m = fmaxf(m, __shfl_xor(m, off));
    __shared__ float sm[4];
    int lane = threadIdx.x & 63, w = threadIdx.x >> 6;
    if (lane == 0) sm[w] = m;
    __syncthreads();
    if (threadIdx.x == 0) {
        m = fmaxf(fmaxf(sm[0], sm[1]), fmaxf(sm[2], sm[3]));
        atomicMax(amax, __float_as_uint(m));  // positive floats: uint compare == float compare
    }
}

// ---------------- Kernel 2: per-row weight quant + bias quant ----------------
__global__ void quantw_kernel(const float* __restrict__ w, const float* __restrict__ bias,
                              const unsigned* __restrict__ amax,
                              char* __restrict__ wq, float* __restrict__ cs, float* __restrict__ bq) {
    int gid = blockIdx.x * blockDim.x + threadIdx.x;
    int row = gid >> 6, lane = gid & 63;
    const float4* r4 = (const float4*)(w + (long)row * DIN);
    float4 a = r4[lane * 2];
    float4 b = r4[lane * 2 + 1];
    float m = fmaxf(fmaxf(fmaxf(fabsf(a.x), fabsf(a.y)), fabsf(a.z)),
                    fmaxf(fmaxf(fabsf(a.w), fabsf(b.x)),
                          fmaxf(fmaxf(fabsf(b.y), fabsf(b.z)), fabsf(b.w))));
#pragma unroll
    for (int off = 32; off; off >>= 1) m = fmaxf(m, __shfl_xor(m, off));
    float wsc = m / 127.0f;
    int lo = q8f(a.x, wsc) | (q8f(a.y, wsc) << 8) | (q8f(a.z, wsc) << 16) | (q8f(a.w, wsc) << 24);
    int hi = q8f(b.x, wsc) | (q8f(b.y, wsc) << 8) | (q8f(b.z, wsc) << 16) | (q8f(b.w, wsc) << 24);
    ((int2*)(wq + (long)row * DIN))[lane] = make_int2(lo, hi);
    if (lane == 0) {
        float as = __uint_as_float(*amax) / 127.0f;
        float bs = as * wsc;
        float t  = rintf(bias[row] / bs);
        cs[row] = bs;
        bq[row] = t * bs;
    }
}

// ---------------- Kernel 3: fused quantize-x + int8 MFMA GEMM ----------------
// BM=64, BN=512 (x read exactly once), BK=64. 512 thr = 8 waves, wave tile 64x64.
// acc[4][4] = 64 regs -> ~110 total/wave -> 2 blocks/CU with 72KB dbuf LDS.
// LDS chunk-linear layout: chunk(row,kc) = (row>>4)*64 + kc*16 + (row&15); every
// MFMA fragment read is base + lane*16 (conflict-free), and w staging satisfies
// global_load_lds's wave-uniform-base + lane*16 constraint.
__global__ __launch_bounds__(512, 4) void gemm_kernel(
    const float* __restrict__ x, const char* __restrict__ wq,
    const float* __restrict__ cs, const float* __restrict__ bq,
    const unsigned* __restrict__ amax, float* __restrict__ out) {
    __shared__ char xl[2][BM * BK];     // 2 x 4 KB
    __shared__ char wl[2][DOUT * BK];   // 2 x 32 KB
    const int t = threadIdx.x;
    const int lane = t & 63, wid = t >> 6;
    const long rbase = (long)(gridDim.x - 1 - blockIdx.x) * BM;  // reverse: L3-recency from absmax sweep
    const float as = __uint_as_float(*amax) / 127.0f;
    const float inv_as = 1.0f / as;

    // x staging: thread t -> row t>>3, 8 floats at col (t&7)*8
    const int xrow = t >> 3;
    const int xcol = (t & 7) * 8;
    const float* xg = x + (rbase + xrow) * DIN + xcol;
    const int xw_off = ((xrow >> 4) * 64 + (xcol >> 4) * 16 + (xrow & 15)) * 16 + (xcol & 15); // 8B aligned

    float4 xr0, xr1;
    v4i acc[4][4] = {};

    auto stage_w = [&](int k0, int b) {
#pragma unroll
        for (int j = 0; j < 4; j++) {
            int g = wid + j * 8;                       // chunk-group 0..31
            int n = g * 16 + (lane & 15);
            int kc = lane >> 4;
            const char* src = wq + (long)n * DIN + k0 + kc * 16;
            __builtin_amdgcn_global_load_lds(
                (const __attribute__((address_space(1))) unsigned int*)src,
                (__attribute__((address_space(3))) unsigned int*)&wl[b][g * 1024],
                16, 0, 0);
        }
    };
    auto x_load = [&](int k0) {
        const float4* p = (const float4*)(xg + k0);
        xr0 = p[0];
        xr1 = p[1];
    };
    auto x_quant = [&](int b) {
        int lo = q8m(xr0.x, inv_as) | (q8m(xr0.y, inv_as) << 8) |
                 (q8m(xr0.z, inv_as) << 16) | (q8m(xr0.w, inv_as) << 24);
        int hi = q8m(xr1.x, inv_as) | (q8m(xr1.y, inv_as) << 8) |
                 (q8m(xr1.z, inv_as) << 16) | (q8m(xr1.w, inv_as) << 24);
        *(int2*)&xl[b][xw_off] = make_int2(lo, hi);
    };

    // prologue
    x_load(0);
    stage_w(0, 0);
    x_quant(0);
    __syncthreads();   // drains vmcnt (gload_lds) + lgkm (ds_write)

    int b = 0;
    for (int ks = 0; ks < NKSTEP; ks++) {
        const int k0n = (ks + 1) * BK;
        if (ks + 1 < NKSTEP) {
            stage_w(k0n, b ^ 1);   // issue next-tile loads BEFORE compute
            x_load(k0n);
        }
        v4i af[4];
#pragma unroll
        for (int mi = 0; mi < 4; mi++)
            af[mi] = *(const v4i*)&xl[b][(mi * 64 + lane) * 16];
#pragma unroll
        for (int ni = 0; ni < 4; ni++) {
            v4i bf = *(const v4i*)&wl[b][((wid * 4 + ni) * 64 + lane) * 16];
#pragma unroll
            for (int mi = 0; mi < 4; mi++)
                acc[mi][ni] = __builtin_amdgcn_mfma_i32_16x16x64_i8(af[mi], bf, acc[mi][ni], 0, 0, 0);
        }
        if (ks + 1 < NKSTEP) x_quant(b ^ 1);  // vmcnt wait for x regs lands here, after MFMA
        __syncthreads();
        b ^= 1;
    }

    // epilogue: C/D layout col = lane&15, row = (lane>>4)*4 + r
    const int rloc = (lane >> 4) * 4;
    const int cloc = lane & 15;
#pragma unroll
    for (int ni = 0; ni < 4; ni++) {
        int col = wid * 64 + ni * 16 + cloc;
        float c = cs[col], bb = bq[col];
#pragma unroll
        for (int mi = 0; mi < 4; mi++) {
            long grow = rbase + mi * 16 + rloc;
#pragma unroll
            for (int r = 0; r < 4; r++)
                out[(grow + r) * DOUT + col] = (float)acc[mi][ni][r] * c + bb;
        }
    }
}

extern "C" void kernel_launch(void* const* d_in, const int* in_sizes, int n_in,
                              void* d_out, int out_size, void* d_ws, size_t ws_size,
                              hipStream_t stream) {
    const float* x    = (const float*)d_in[0];
    const float* w    = (const float*)d_in[1];
    const float* bias = (const float*)d_in[2];
    float* out = (float*)d_out;
    const int M = in_sizes[0] / DIN;   // 65536

    char* ws = (char*)d_ws;
    unsigned* amax = (unsigned*)ws;
    char* wq  = ws + 64;
    float* cs = (float*)(ws + 64 + (long)DOUT * DIN);
    float* bq = cs + DOUT;

    hipMemsetAsync(d_ws, 0, 64, stream);
    absmax_kernel<<<2048, 256, 0, stream>>>((const float4*)x, amax, in_sizes[0] / 4);
    quantw_kernel<<<(DOUT * 64) / 256, 256, 0, stream>>>(w, bias, amax, wq, cs, bq);
    gemm_kernel<<<M / BM, 512, 0, stream>>>(x, wq, cs, bq, amax, out);
}

// Round 3
// 112.205 us; speedup vs baseline: 1.0232x; 1.0020x over previous
//
#include <hip/hip_runtime.h>

#define DIN 512
#define DOUT 512
#define BM 64
#define BK 64
#define NK (DIN / BK)

typedef int v4i __attribute__((ext_vector_type(4)));
typedef float v4f __attribute__((ext_vector_type(4)));

// exact-divide quantize (weights path, matches ref bit-for-bit)
__device__ __forceinline__ int q8f(float v, float s) {
    int i = (int)rintf(v / s);
    i = i < -128 ? -128 : (i > 127 ? 127 : i);
    return i & 255;
}
// multiply-by-reciprocal quantize (activation path; flip prob ~2^-22, contribution ~0.005 << 0.0525)
__device__ __forceinline__ int q8m(float v, float inv) {
    int i = (int)rintf(v * inv);
    i = i < -128 ? -128 : (i > 127 ? 127 : i);
    return i & 255;
}

// ---------------- Kernel 1: global absmax of x ----------------
__global__ void absmax_kernel(const float4* __restrict__ x4, unsigned* __restrict__ amax, int n4) {
    float m = 0.f;
    int stride = gridDim.x * blockDim.x;
    for (int i = blockIdx.x * blockDim.x + threadIdx.x; i < n4; i += stride) {
        float4 v = x4[i];
        m = fmaxf(m, fmaxf(fmaxf(fabsf(v.x), fabsf(v.y)), fmaxf(fabsf(v.z), fabsf(v.w))));
    }
#pragma unroll
    for (int off = 32; off; off >>= 1) m = fmaxf(m, __shfl_xor(m, off));
    __shared__ float sm[4];
    int lane = threadIdx.x & 63, w = threadIdx.x >> 6;
    if (lane == 0) sm[w] = m;
    __syncthreads();
    if (threadIdx.x == 0) {
        m = fmaxf(fmaxf(sm[0], sm[1]), fmaxf(sm[2], sm[3]));
        atomicMax(amax, __float_as_uint(m));  // positive floats: uint compare == float compare
    }
}

// ---------------- Kernel 2: per-row weight quant (no amax dependency) ----------------
__global__ void quantw_kernel(const float* __restrict__ w,
                              char* __restrict__ wq, float* __restrict__ wsc) {
    int gid = blockIdx.x * blockDim.x + threadIdx.x;
    int row = gid >> 6, lane = gid & 63;
    const float4* r4 = (const float4*)(w + (long)row * DIN);
    float4 a = r4[lane * 2];
    float4 b = r4[lane * 2 + 1];
    float m = fmaxf(fmaxf(fmaxf(fabsf(a.x), fabsf(a.y)), fmaxf(fabsf(a.z), fabsf(a.w))),
                    fmaxf(fmaxf(fabsf(b.x), fabsf(b.y)), fmaxf(fabsf(b.z), fabsf(b.w))));
#pragma unroll
    for (int off = 32; off; off >>= 1) m = fmaxf(m, __shfl_xor(m, off));
    float s = m / 127.0f;
    int lo = q8f(a.x, s) | (q8f(a.y, s) << 8) | (q8f(a.z, s) << 16) | (q8f(a.w, s) << 24);
    int hi = q8f(b.x, s) | (q8f(b.y, s) << 8) | (q8f(b.z, s) << 16) | (q8f(b.w, s) << 24);
    ((int2*)(wq + (long)row * DIN))[lane] = make_int2(lo, hi);
    if (lane == 0) wsc[row] = s;
}

// ---------------- Kernel 3: fused quantize-x + int8 MFMA GEMM ----------------
// BM=64, BN=512 (x read exactly once), BK=64. 512 thr = 8 waves; wave = 64 m x 64 oc.
// A-operand = w (direct L2->reg, 1-step prefetch, no LDS), B-operand = x (LDS dbuf 2x4KB,
// chunk-linear layout -> every ds_read_b128 is base+lane*16, conflict-free).
// Raw s_barrier + lgkmcnt(0): global reg-loads stay in flight across barriers.
// D layout: row = oc (lane>>4)*4+r -> 4 CONSECUTIVE out floats per lane -> float4 nt stores.
__global__ __launch_bounds__(512, 4) void gemm_kernel(
    const float* __restrict__ x, const char* __restrict__ wq,
    const float* __restrict__ wsc, const float* __restrict__ bias,
    const unsigned* __restrict__ amax, float* __restrict__ out) {
    __shared__ char xl[2][BM * BK];   // 2 x 4 KB
    const int t = threadIdx.x;
    const int lane = t & 63, wid = t >> 6;
    const long rbase = (long)(gridDim.x - 1 - blockIdx.x) * BM;  // reverse: L3 recency from absmax sweep
    const float as = __uint_as_float(*amax) / 127.0f;
    const float inv_as = 1.0f / as;

    // x staging: thread t -> row t>>3, 8 floats at col (t&7)*8
    const int xrow = t >> 3, xc = t & 7;
    const float4* xg = (const float4*)(x + (rbase + xrow) * DIN) + xc * 2;
    const int xw_off = ((xrow >> 4) * 64 + (xc >> 1) * 16 + (xrow & 15)) * 16 + (xc & 1) * 8;

    // w fragment base: frag ni at step ks -> wg + ni*16*DIN + ks*BK
    const char* wg = wq + (wid * 64 + (lane & 15)) * DIN + (lane >> 4) * 16;

    float4 xr[2][2];   // 2-deep x prefetch
    v4i wr[2][4];      // 1-step w prefetch
    v4i acc[4][4] = {};

    auto ldx = [&](int s, int set) {
        const float4* p = xg + s * 16;
        xr[set][0] = p[0];
        xr[set][1] = p[1];
    };
    auto ldw = [&](int s, int set) {
#pragma unroll
        for (int ni = 0; ni < 4; ni++)
            wr[set][ni] = *(const v4i*)(wg + ni * 16 * DIN + s * BK);
    };
    auto qx = [&](int set, int b) {
        float4 a = xr[set][0], c = xr[set][1];
        int lo = q8m(a.x, inv_as) | (q8m(a.y, inv_as) << 8) |
                 (q8m(a.z, inv_as) << 16) | (q8m(a.w, inv_as) << 24);
        int hi = q8m(c.x, inv_as) | (q8m(c.y, inv_as) << 8) |
                 (q8m(c.z, inv_as) << 16) | (q8m(c.w, inv_as) << 24);
        *(int2*)&xl[b][xw_off] = make_int2(lo, hi);
    };

#define LGKM0_BARRIER() do { asm volatile("s_waitcnt lgkmcnt(0)" ::: "memory"); \
                             __builtin_amdgcn_s_barrier(); } while (0)

    // prologue
    ldx(0, 0);
    ldw(0, 0);
    ldx(1, 1);
    qx(0, 0);
    LGKM0_BARRIER();

#pragma unroll
    for (int ks = 0; ks < NK; ks++) {
        if (ks + 2 < NK) ldx(ks + 2, ks & 1);          // issue x(ks+2), set freed by quant of x(ks)
        if (ks + 1 < NK) ldw(ks + 1, (ks + 1) & 1);    // issue w(ks+1)
        if (ks + 1 < NK) qx((ks + 1) & 1, (ks + 1) & 1); // quant x(ks+1) -> other buffer
        v4i bf[4];
#pragma unroll
        for (int mi = 0; mi < 4; mi++)
            bf[mi] = *(const v4i*)&xl[ks & 1][(mi * 64 + lane) * 16];
#pragma unroll
        for (int ni = 0; ni < 4; ni++)
#pragma unroll
            for (int mi = 0; mi < 4; mi++)
                acc[mi][ni] = __builtin_amdgcn_mfma_i32_16x16x64_i8(wr[ks & 1][ni], bf[mi], acc[mi][ni], 0, 0, 0);
        if (ks + 1 < NK) LGKM0_BARRIER();
    }

    // epilogue: D row = oc local = (lane>>4)*4+r, col = m local = lane&15
    const int mloc = lane & 15;
    const int ocr = (lane >> 4) * 4;
#pragma unroll
    for (int ni = 0; ni < 4; ni++) {
        int oc0 = wid * 64 + ni * 16 + ocr;
        float4 w4 = *(const float4*)(wsc + oc0);
        float4 b4 = *(const float4*)(bias + oc0);
        float bs0 = as * w4.x, bs1 = as * w4.y, bs2 = as * w4.z, bs3 = as * w4.w;
        float q0 = rintf(b4.x / bs0) * bs0;
        float q1 = rintf(b4.y / bs1) * bs1;
        float q2 = rintf(b4.z / bs2) * bs2;
        float q3 = rintf(b4.w / bs3) * bs3;
#pragma unroll
        for (int mi = 0; mi < 4; mi++) {
            long m = rbase + mi * 16 + mloc;
            v4f v;
            v[0] = (float)acc[mi][ni][0] * bs0 + q0;
            v[1] = (float)acc[mi][ni][1] * bs1 + q1;
            v[2] = (float)acc[mi][ni][2] * bs2 + q2;
            v[3] = (float)acc[mi][ni][3] * bs3 + q3;
            __builtin_nontemporal_store(v, (v4f*)(out + m * DOUT + oc0));
        }
    }
}

extern "C" void kernel_launch(void* const* d_in, const int* in_sizes, int n_in,
                              void* d_out, int out_size, void* d_ws, size_t ws_size,
                              hipStream_t stream) {
    const float* x    = (const float*)d_in[0];
    const float* w    = (const float*)d_in[1];
    const float* bias = (const float*)d_in[2];
    float* out = (float*)d_out;
    const int M = in_sizes[0] / DIN;   // 65536

    char* ws = (char*)d_ws;
    unsigned* amax = (unsigned*)ws;
    char* wq   = ws + 64;
    float* wsc = (float*)(ws + 64 + (long)DOUT * DIN);

    hipMemsetAsync(d_ws, 0, 64, stream);
    quantw_kernel<<<(DOUT * 64) / 256, 256, 0, stream>>>(w, wq, wsc);
    absmax_kernel<<<2048, 256, 0, stream>>>((const float4*)x, amax, in_sizes[0] / 4);
    gemm_kernel<<<M / BM, 512, 0, stream>>>(x, wq, wsc, bias, amax, out);
}